// Round 2
// baseline (249.561 us; speedup 1.0000x reference)
//
#include <hip/hip_runtime.h>
#include <math.h>

// Sobel 3D magnitude, separable: S=[1,2,1], D=[1,0,-1]
// gx = Sz(Sy(Dx)), gy = Sz(Dy(Sx)), gz = Dz(Sy(Sx)); out = sqrt(gx^2+gy^2+gz^2+1e-6)
// x: (2,32,64,128,128) fp32. Double-buffered LDS planes, 1 barrier/z-iter,
// aligned b128 LDS reads + shuffle w-halo (no bank conflicts), z split in 2 chunks
// for 8 blocks/CU occupancy.

constexpr int W   = 128;
constexpr int H   = 128;
constexpr int DZ  = 64;
constexpr int NC  = 2 * 32;
constexpr int TH  = 8;            // output rows per block
constexpr int HBLKS = H / TH;     // 16
constexpr int ZCH = 2;            // z chunks
constexpr int ZLEN = DZ / ZCH;    // 32
constexpr int LROWS = TH + 2;     // 10 staged rows (y-halo)

__global__ __launch_bounds__(256, 8)
void sobel3d_kernel(const float* __restrict__ xg, float* __restrict__ og) {
    const int tid = threadIdx.x;
    const int tx  = tid & 31;      // w segment: pixels 4*tx..4*tx+3
    const int ty  = tid >> 5;      // row 0..7
    int b = blockIdx.x;
    const int hblk = b % HBLKS; b /= HBLKS;
    const int zc   = b % ZCH;   b /= ZCH;
    const int nc   = b;
    const int h0   = hblk * TH;
    const int za   = zc * ZLEN;
    const int zb   = za + ZLEN;    // exclusive

    const float* __restrict__ xp = xg + (size_t)nc * DZ * H * W;
    float* __restrict__ op       = og + (size_t)nc * DZ * H * W;

    __shared__ float lds[2][LROWS][W];

    // staging assignment: part0 = all 256 threads -> rows 0..7; part1 = tid<64 -> rows 8..9
    const int  r0    = ty;
    const int  h_a   = h0 - 1 + r0;
    const bool has1  = (tid < 64);
    const int  r1    = 8 + ty;          // valid only when has1 (ty in {0,1})
    const int  h_b   = h0 - 1 + r1;

    auto gload = [&](int z, int h) -> float4 {
        if ((unsigned)z < (unsigned)DZ && (unsigned)h < (unsigned)H)
            return *(const float4*)(xp + ((size_t)z * H + h) * W + 4 * tx);
        return make_float4(0.f, 0.f, 0.f, 0.f);
    };
    auto lwrite = [&](int buf, float4 v0, float4 v1) {
        *(float4*)&lds[buf][r0][4 * tx] = v0;
        if (has1) *(float4*)&lds[buf][r1][4 * tx] = v1;
    };

    // xy-separable intermediates for this thread's 4 pixels from plane in buf
    auto compute_plane = [&](int buf, float* c, float* d, float* e) {
        float sx[3][4], dx[3][4];
#pragma unroll
        for (int k = 0; k < 3; ++k) {
            float4 q = *(const float4*)&lds[buf][ty + k][4 * tx];
            float xm1 = __shfl_up(q.w, 1, 64);
            if (tx == 0)  xm1 = 0.f;
            float xp4 = __shfl_down(q.x, 1, 64);
            if (tx == 31) xp4 = 0.f;
            sx[k][0] = xm1 + 2.f * q.x + q.y;
            sx[k][1] = q.x + 2.f * q.y + q.z;
            sx[k][2] = q.y + 2.f * q.z + q.w;
            sx[k][3] = q.z + 2.f * q.w + xp4;
            dx[k][0] = xm1 - q.y;
            dx[k][1] = q.x - q.z;
            dx[k][2] = q.y - q.w;
            dx[k][3] = q.z - xp4;
        }
#pragma unroll
        for (int i = 0; i < 4; ++i) {
            c[i] = sx[0][i] + 2.f * sx[1][i] + sx[2][i];  // Sy(Sx)
            d[i] = sx[0][i] - sx[2][i];                   // Dy(Sx)
            e[i] = dx[0][i] + 2.f * dx[1][i] + dx[2][i];  // Sy(Dx)
        }
    };

    float c0[4], d0[4], e0[4], c1[4], d1[4], e1[4], c2[4], d2[4], e2[4];

    // ---- prologue: planes za-1 -> buf0, za -> buf1, za+1 -> buf0 ----
    {
        float4 a0 = gload(za - 1, h_a), a1 = gload(za - 1, h_b);
        float4 b0 = gload(za,     h_a), b1 = gload(za,     h_b);
        lwrite(0, a0, a1);
        lwrite(1, b0, b1);
    }
    __syncthreads();
    compute_plane(0, c0, d0, e0);   // plane za-1
    compute_plane(1, c1, d1, e1);   // plane za
    {
        float4 p0 = gload(za + 1, h_a), p1 = gload(za + 1, h_b);
        __syncthreads();            // everyone done reading buf0
        lwrite(0, p0, p1);
    }
    __syncthreads();
    int cur = 0;                    // buf[cur] holds plane z+1 at loop top

    for (int z = za; z < zb; ++z) {
        // issue next-next plane load (z+2); skip planes beyond this chunk's need
        int zn = z + 2;
        if (zn > zb) zn = -1;       // -> zeros, avoids wasted fetch
        float4 n0 = gload(zn, h_a), n1 = gload(zn, h_b);

        // compute plane z+1 from buf[cur] (hides the global-load latency)
        compute_plane(cur, c2, d2, e2);

        // stage plane z+2 into the other buffer (its old contents were
        // consumed before the previous barrier)
        lwrite(cur ^ 1, n0, n1);

        // emit output plane z
        float4 o;
        float r[4];
#pragma unroll
        for (int i = 0; i < 4; ++i) {
            float gx = e0[i] + 2.f * e1[i] + e2[i];
            float gy = d0[i] + 2.f * d1[i] + d2[i];
            float gz = c0[i] - c2[i];
            r[i] = __builtin_amdgcn_sqrtf(gx * gx + gy * gy + gz * gz + 1e-6f);
        }
        o.x = r[0]; o.y = r[1]; o.z = r[2]; o.w = r[3];
        *(float4*)(op + ((size_t)z * H + (h0 + ty)) * W + 4 * tx) = o;

        // shift rolling window
#pragma unroll
        for (int i = 0; i < 4; ++i) {
            c0[i] = c1[i]; c1[i] = c2[i];
            d0[i] = d1[i]; d1[i] = d2[i];
            e0[i] = e1[i]; e1[i] = e2[i];
        }
        __syncthreads();
        cur ^= 1;
    }
}

extern "C" void kernel_launch(void* const* d_in, const int* in_sizes, int n_in,
                              void* d_out, int out_size, void* d_ws, size_t ws_size,
                              hipStream_t stream) {
    const float* x = (const float*)d_in[0];
    float* out = (float*)d_out;
    dim3 grid(NC * ZCH * HBLKS);   // 64*2*16 = 2048 blocks -> 8/CU
    dim3 block(256);
    sobel3d_kernel<<<grid, block, 0, stream>>>(x, out);
}

// Round 3
// 134.282 us; speedup vs baseline: 1.8585x; 1.8585x over previous
//
#include <hip/hip_runtime.h>
#include <math.h>

// Sobel 3D magnitude, separable: S=[1,2,1], D=[1,0,-1]
// gx = Sz(Sy(Dx)), gy = Sz(Dy(Sx)), gz = Dz(Sy(Sx)); out = sqrt(gx^2+gy^2+gz^2+1e-6)
// x: (2,32,64,128,128) fp32.
// R3: R2 pipeline (double-buffered LDS planes, 1 barrier/iter, shuffle w-halo)
// with spill eliminated: 2-plane rolling state (24 floats), launch_bounds(256,6),
// nontemporal output stores.

typedef float floatx4 __attribute__((ext_vector_type(4)));

constexpr int W   = 128;
constexpr int H   = 128;
constexpr int DZ  = 64;
constexpr int NC  = 2 * 32;
constexpr int TH  = 8;            // output rows per block
constexpr int HBLKS = H / TH;     // 16
constexpr int ZCH = 2;            // z chunks
constexpr int ZLEN = DZ / ZCH;    // 32
constexpr int LROWS = TH + 2;     // 10 staged rows (y-halo)

__global__ __launch_bounds__(256, 6)
void sobel3d_kernel(const float* __restrict__ xg, float* __restrict__ og) {
    const int tid = threadIdx.x;
    const int tx  = tid & 31;      // w segment: pixels 4*tx..4*tx+3
    const int ty  = tid >> 5;      // row 0..7
    int b = blockIdx.x;
    const int hblk = b % HBLKS; b /= HBLKS;
    const int zc   = b % ZCH;   b /= ZCH;
    const int nc   = b;
    const int h0   = hblk * TH;
    const int za   = zc * ZLEN;
    const int zb   = za + ZLEN;    // exclusive

    const float* __restrict__ xp = xg + (size_t)nc * DZ * H * W;
    float* __restrict__ op       = og + (size_t)nc * DZ * H * W;

    __shared__ float lds[2][LROWS][W];

    // staging: all 256 threads -> rows 0..7; tid<64 additionally -> rows 8..9
    const int  r0   = ty;
    const int  h_a  = h0 - 1 + r0;
    const bool has1 = (tid < 64);
    const int  r1   = 8 + ty;
    const int  h_b  = h0 - 1 + r1;

    auto gload = [&](int z, int h) -> floatx4 {
        if ((unsigned)z < (unsigned)DZ && (unsigned)h < (unsigned)H)
            return *(const floatx4*)(xp + ((size_t)z * H + h) * W + 4 * tx);
        return (floatx4){0.f, 0.f, 0.f, 0.f};
    };
    auto lwrite = [&](int buf, floatx4 v0, floatx4 v1) {
        *(floatx4*)&lds[buf][r0][4 * tx] = v0;
        if (has1) *(floatx4*)&lds[buf][r1][4 * tx] = v1;
    };

    // row horizontal pass: Sx, Dx for this thread's 4 pixels of one LDS row
    auto row_sd = [&](int buf, int row, floatx4& s, floatx4& d) {
        floatx4 q = *(const floatx4*)&lds[buf][row][4 * tx];
        float xm1 = __shfl_up(q.w, 1, 64);
        if (tx == 0)  xm1 = 0.f;
        float xp4 = __shfl_down(q.x, 1, 64);
        if (tx == 31) xp4 = 0.f;
        s.x = xm1 + 2.f * q.x + q.y;
        s.y = q.x + 2.f * q.y + q.z;
        s.z = q.y + 2.f * q.z + q.w;
        s.w = q.z + 2.f * q.w + xp4;
        d.x = xm1 - q.y;
        d.y = q.x - q.z;
        d.z = q.y - q.w;
        d.w = q.z - xp4;
    };

    // full xy pass for the plane in buf: c=Sy(Sx), d=Dy(Sx), e=Sy(Dx)
    auto compute_plane = [&](int buf, floatx4& cc, floatx4& dd, floatx4& ee) {
        floatx4 sA, dA, sB, dB, sC, dC;
        row_sd(buf, ty,     sA, dA);
        row_sd(buf, ty + 1, sB, dB);
        row_sd(buf, ty + 2, sC, dC);
        cc = sA + 2.f * sB + sC;
        dd = sA - sC;
        ee = dA + 2.f * dB + dC;
    };

    // rolling 2-plane state: prev (z-1) and curr (z) intermediates
    floatx4 cP, dP, eP, cC, dC_, eC;

    // ---- prologue: za-1 -> buf0, za -> buf1, za+1 -> buf0 ----
    {
        floatx4 a0 = gload(za - 1, h_a), a1 = gload(za - 1, h_b);
        floatx4 b0 = gload(za,     h_a), b1 = gload(za,     h_b);
        lwrite(0, a0, a1);
        lwrite(1, b0, b1);
    }
    __syncthreads();
    compute_plane(0, cP, dP, eP);   // plane za-1
    compute_plane(1, cC, dC_, eC);  // plane za
    {
        floatx4 p0 = gload(za + 1, h_a), p1 = gload(za + 1, h_b);
        __syncthreads();            // all waves done reading buf0
        lwrite(0, p0, p1);
    }
    __syncthreads();
    int cur = 0;                    // buf[cur] holds plane z+1 at loop top

    size_t obase = ((size_t)za * H + (h0 + ty)) * W + 4 * tx;
    const size_t ostep = (size_t)H * W;

    for (int z = za; z < zb; ++z) {
        // issue plane z+2 load (beyond chunk need -> zeros, no fetch)
        int zn = z + 2;
        if (zn > zb) zn = -1;
        floatx4 n0 = gload(zn, h_a), n1 = gload(zn, h_b);

        // compute plane z+1 from buf[cur] (hides global-load latency)
        floatx4 c2, d2, e2;
        compute_plane(cur, c2, d2, e2);

        // stage plane z+2 (old contents consumed before previous barrier)
        lwrite(cur ^ 1, n0, n1);

        // emit output plane z
        floatx4 gx = eP + 2.f * eC + e2;
        floatx4 gy = dP + 2.f * dC_ + d2;
        floatx4 gz = cP - c2;
        floatx4 o;
        o.x = __builtin_amdgcn_sqrtf(gx.x * gx.x + gy.x * gy.x + gz.x * gz.x + 1e-6f);
        o.y = __builtin_amdgcn_sqrtf(gx.y * gx.y + gy.y * gy.y + gz.y * gz.y + 1e-6f);
        o.z = __builtin_amdgcn_sqrtf(gx.z * gx.z + gy.z * gy.z + gz.z * gz.z + 1e-6f);
        o.w = __builtin_amdgcn_sqrtf(gx.w * gx.w + gy.w * gy.w + gz.w * gz.w + 1e-6f);
        __builtin_nontemporal_store(o, (floatx4*)(op + obase));

        // shift rolling window (prev <- curr <- new)
        cP = cC; cC = c2;
        dP = dC_; dC_ = d2;
        eP = eC; eC = e2;
        obase += ostep;

        __syncthreads();
        cur ^= 1;
    }
}

extern "C" void kernel_launch(void* const* d_in, const int* in_sizes, int n_in,
                              void* d_out, int out_size, void* d_ws, size_t ws_size,
                              hipStream_t stream) {
    const float* x = (const float*)d_in[0];
    float* out = (float*)d_out;
    dim3 grid(NC * ZCH * HBLKS);   // 64*2*16 = 2048 blocks
    dim3 block(256);
    sobel3d_kernel<<<grid, block, 0, stream>>>(x, out);
}